// Round 4
// baseline (355.993 us; speedup 1.0000x reference)
//
#include <hip/hip_runtime.h>
#include <hip/hip_fp16.h>
#include <math.h>

#define WAVE   64
#define NPB    32          // nodes per window
#define BLOCKT 256
#define SMAX   2           // stashed 1024-edge chunks (covers <=2048 edges/window)
#define PBLOCKS 2048       // persistent blocks (8 per CU)

// ---- constants from the reference ----
#define KC        2.2281692032865347f   // 7/pi
#define H         0.05f
#define INV_H2    400.0f
#define INV_H3    8000.0f
#define EPS_REF   0.00025f              // h^2 * 0.1
#define K_OUT     0.24261080f           // 2*h*DELTA*C0
#define REST_RHO  1000.0f

__device__ __forceinline__ float wendland_dkdq(float q) {
    float o = 1.f - q;
    return -20.f * q * o * o * o * KC;
}

union H2F { __half2 h; float f; };
__device__ __forceinline__ float   h2_as_f(__half2 h) { H2F u; u.h = h; return u.f; }
__device__ __forceinline__ __half2 f_as_h2(float f)   { H2F u; u.f = f; return u.h; }

// largest li in [0,NPB) with rp[li] <= e   (rp[0] <= e < rp[NPB] guaranteed)
__device__ __forceinline__ int li_search(const int* rp, int e) {
    int lo = 0;
#pragma unroll
    for (int s = NPB / 2; s >= 1; s >>= 1) lo += (rp[lo + s] <= e) ? s : 0;
    return lo;
}

// ---------------------------------------------------------------------------
// 4-edge-per-lane segmented reduction via shuffle scan (proven R0 structure).
// Equal keys contiguous in lane order; key<0 skipped. base may be LDS.
// Scan capped at d<=16: reach 31 lanes -> correct for runs up to ~124 edges;
// degrees are ~Poisson(32), max ~64 -> 2x margin.
// ---------------------------------------------------------------------------
template<int NV>
__device__ __forceinline__ void seg_reduce4(const int k[4], float v[4][NV], float* base) {
    const int lane = threadIdx.x & (WAVE - 1);
    const int k0 = k[0], k3 = k[3];
    const bool split = (k0 != k3);
    const int firstLen  = (k[1]==k0) ? ((k[2]==k0) ? ((k[3]==k0)?4:3) : 2) : 1;
    const int lastStart = (k[2]==k3) ? ((k[1]==k3) ? ((k[0]==k3)?0:1) : 2) : 3;

    float vin[NV], vfirst[NV];
#pragma unroll
    for (int c = 0; c < NV; ++c) {
        float s = v[3][c];
        if (lastStart <= 2) s += v[2][c];
        if (lastStart <= 1) s += v[1][c];
        if (lastStart == 0) s += v[0][c];
        vin[c] = s;
        float f = v[0][c];
        if (firstLen >= 2) f += v[1][c];
        if (firstLen >= 3) f += v[2][c];
        if (firstLen >= 4) f += v[3][c];
        vfirst[c] = f;
    }
#pragma unroll
    for (int idx = 1; idx <= 2; ++idx) {
        if (idx >= firstLen && idx < lastStart && k[idx] >= 0) {
#pragma unroll
            for (int c = 0; c < NV; ++c)
                atomicAdd(base + (size_t)k[idx] * NV + c, v[idx][c]);
        }
    }
    float S[NV];
#pragma unroll
    for (int c = 0; c < NV; ++c) S[c] = vin[c];
    const int klast = k3;
#pragma unroll
    for (int d = 1; d <= 16; d <<= 1) {   // 5 steps (bound above)
        int okey = __shfl_up(klast, d, WAVE);
        float ov[NV];
#pragma unroll
        for (int c = 0; c < NV; ++c) ov[c] = __shfl_up(S[c], d, WAVE);
        if (lane >= d && okey == klast) {
#pragma unroll
            for (int c = 0; c < NV; ++c) S[c] += ov[c];
        }
    }
    const int prevk = __shfl_up(klast, 1, WAVE);
    float P[NV];
#pragma unroll
    for (int c = 0; c < NV; ++c) P[c] = __shfl_up(S[c], 1, WAVE);
    if (split && k0 >= 0) {
        const bool carry = (lane > 0 && prevk == k0);
#pragma unroll
        for (int c = 0; c < NV; ++c)
            atomicAdd(base + (size_t)k0 * NV + c, vfirst[c] + (carry ? P[c] : 0.f));
    }
    const int nk0 = __shfl_down(k0, 1, WAVE);
    const bool tail = (lane == WAVE - 1) || (nk0 != klast);
    if (tail && klast >= 0) {
#pragma unroll
        for (int c = 0; c < NV; ++c)
            atomicAdd(base + (size_t)klast * NV + c, S[c]);
    }
}

struct EW { int jv[4]; float qv[4], dxv[4], dyv[4]; bool okv[4]; };

__device__ __forceinline__ void load_win(long e0, int beg, int end, int E,
        const int* __restrict__ ej, const float* __restrict__ qarr,
        const float2* __restrict__ dirs, EW& w) {
    if (e0 + 3 < (long)E) {
        int4   j4 = *(const int4*)(ej + e0);
        float4 q4 = *(const float4*)(qarr + e0);
        float4 dA = *(const float4*)((const float*)dirs + 2 * e0);
        float4 dB = *(const float4*)((const float*)dirs + 2 * e0 + 4);
        w.jv[0]=j4.x; w.jv[1]=j4.y; w.jv[2]=j4.z; w.jv[3]=j4.w;
        w.qv[0]=q4.x; w.qv[1]=q4.y; w.qv[2]=q4.z; w.qv[3]=q4.w;
        w.dxv[0]=dA.x; w.dyv[0]=dA.y; w.dxv[1]=dA.z; w.dyv[1]=dA.w;
        w.dxv[2]=dB.x; w.dyv[2]=dB.y; w.dxv[3]=dB.z; w.dyv[3]=dB.w;
    } else {
#pragma unroll
        for (int u = 0; u < 4; ++u) {
            long e = e0 + u;
            if (e < (long)E) {
                w.jv[u] = ej[e]; w.qv[u] = qarr[e];
                float2 d = dirs[e]; w.dxv[u] = d.x; w.dyv[u] = d.y;
            } else { w.jv[u]=0; w.qv[u]=0.f; w.dxv[u]=0.f; w.dyv[u]=0.f; }
        }
    }
#pragma unroll
    for (int u = 0; u < 4; ++u) {
        long e = e0 + u;
        w.okv[u] = (e >= (long)beg) && (e < (long)end);
    }
}

// rowptr[t] = first edge e with i[e] >= t (i sorted); pack vd; zero tickets.
__global__ void k_prep(const int* __restrict__ ei, const float* __restrict__ vol,
                       const float* __restrict__ dens, int* __restrict__ rowptr,
                       float2* __restrict__ vd, int* __restrict__ tickets,
                       int N, int E) {
    int e = blockIdx.x * blockDim.x + threadIdx.x;
    if (e <= E) {
        int prev = (e == 0) ? -1 : ei[e - 1];
        int cur  = (e == E) ? N  : ei[e];
        for (int t = prev + 1; t <= cur; ++t) rowptr[t] = e;
    }
    if (e < N) vd[e] = make_float2(vol[e], dens[e]);
    if (blockIdx.x == 0 && threadIdx.x < 2) tickets[threadIdx.x] = 0;
}

// Fused A+B+C+term1/2 of D, persistent blocks over ticket-dispensed windows.
__global__ __launch_bounds__(BLOCKT, 4)
void k_AC(const int* __restrict__ ej, const float* __restrict__ qarr,
          const float2* __restrict__ dirs, const float2* __restrict__ vd,
          const int* __restrict__ rowptr, __half2* __restrict__ cst,
          float2* __restrict__ g2, float* __restrict__ outp,
          int* __restrict__ tickets, int N, int E, int nwin) {
    __shared__ int    rp[NPB + 1];
    __shared__ float  acc6[NPB * 6];     // m00,m01,m11,A,Bx,By
    __shared__ float  Lild[NPB * 3];
    __shared__ float  gld[NPB * 2];
    __shared__ float2 vdl[NPB];
    __shared__ int    wsh;
    const int tid = threadIdx.x;
    const int waveBase = tid & ~(WAVE - 1);

    int   li_s[4 * SMAX];
    float gwx_s[4 * SMAX], gwy_s[4 * SMAX], val_s[4 * SMAX];

    for (;;) {
        if (tid == 0) wsh = atomicAdd(&tickets[0], 1);
        __syncthreads();                         // orders prev-window LDS reuse too
        const int w = wsh;
        if (w >= nwin) break;

        const int n0  = w * NPB;
        const int nHi = min(n0 + NPB, N);
        if (tid <= NPB) rp[tid] = rowptr[min(n0 + tid, nHi)];
        if (tid < NPB && n0 + tid < N) vdl[tid] = vd[n0 + tid];
        if (tid < NPB * 6) acc6[tid] = 0.f;
        if (tid < NPB * 2) gld[tid] = 0.f;
        __syncthreads();
        const int  beg = rp[0], end = rp[NPB];
        const long beg4 = (long)beg & ~3L;

#pragma unroll
        for (int x = 0; x < 4 * SMAX; ++x) { li_s[x] = -1; gwx_s[x]=gwy_s[x]=val_s[x]=0.f; }

        // ---- phase A ----
#pragma unroll
        for (int c = 0; c < SMAX; ++c) {
            long ebw = beg4 + ((long)c * BLOCKT + waveBase) * 4;
            if (ebw < (long)end) {
                long e0 = beg4 + ((long)c * BLOCKT + tid) * 4;
                EW wd; load_win(e0, beg, end, E, ej, qarr, dirs, wd);
                const bool all4 = wd.okv[0] && wd.okv[1] && wd.okv[2] && wd.okv[3];
                float4 cpack;
                int k[4]; float v[4][6];
#pragma unroll
                for (int u = 0; u < 4; ++u) {
                    k[u] = -1;
#pragma unroll
                    for (int c2 = 0; c2 < 6; ++c2) v[u][c2] = 0.f;
                    if (wd.okv[u]) {
                        int li = li_search(rp, (int)(e0 + u));
                        float q = wd.qv[u], dx = wd.dxv[u], dy = wd.dyv[u];
                        float2 vdj = vd[wd.jv[u]];
                        float wq = wendland_dkdq(q);
                        float t  = q * wq * INV_H2;      // = w*q*H with w=wq/h^3
                        float s  = -2.f * vdj.x * t;     // >= 0
                        float w2 = wq * INV_H3;
                        float gwx = dx * w2, gwy = dy * w2;
                        float rx = -dx * q * H, ry = -dy * q * H;
                        float rji2 = rx * rx + ry * ry + EPS_REF;
                        float gT = -t / rji2;            // unit dirs: gw.r = -w q H
                        float gv = gT * vdj.x;
                        float rho_ba = REST_RHO * (vdj.y - vdl[li].y);
                        k[u] = li;
                        v[u][0] = s * dx * dx; v[u][1] = s * dx * dy; v[u][2] = s * dy * dy;
                        v[u][3] = rho_ba * gv; v[u][4] = rx * gv;    v[u][5] = ry * gv;
                        __half2 cp = __floats2half2_rn(0.5f * rx * gv, 0.5f * ry * gv);
                        if (all4) (&cpack.x)[u] = h2_as_f(cp);
                        else      cst[e0 + u] = cp;
                        li_s[c*4+u] = li; gwx_s[c*4+u] = gwx; gwy_s[c*4+u] = gwy;
                        val_s[c*4+u] = 2.f * rho_ba * vdj.x;
                    }
                }
                if (all4) ((float4*)cst)[e0 >> 2] = cpack;
                seg_reduce4<6>(k, v, acc6);
            }
        }
        // overflow (window > SMAX*1024 edges; practically never at degree ~32)
        for (int c = SMAX; ; ++c) {
            long ebw = beg4 + ((long)c * BLOCKT + waveBase) * 4;
            if (ebw >= (long)end) break;
            long e0 = beg4 + ((long)c * BLOCKT + tid) * 4;
            EW wd; load_win(e0, beg, end, E, ej, qarr, dirs, wd);
            int k[4]; float v[4][6];
#pragma unroll
            for (int u = 0; u < 4; ++u) {
                k[u] = -1;
#pragma unroll
                for (int c2 = 0; c2 < 6; ++c2) v[u][c2] = 0.f;
                if (wd.okv[u]) {
                    int li = li_search(rp, (int)(e0 + u));
                    float q = wd.qv[u], dx = wd.dxv[u], dy = wd.dyv[u];
                    float2 vdj = vd[wd.jv[u]];
                    float wq = wendland_dkdq(q);
                    float t  = q * wq * INV_H2;
                    float s  = -2.f * vdj.x * t;
                    float w2 = wq * INV_H3;
                    float gwx = dx * w2, gwy = dy * w2;
                    float rx = -dx * q * H, ry = -dy * q * H;
                    float rji2 = rx * rx + ry * ry + EPS_REF;
                    float gT = -t / rji2;
                    float gv = gT * vdj.x;
                    float rho_ba = REST_RHO * (vdj.y - vdl[li].y);
                    k[u] = li;
                    v[u][0] = s * dx * dx; v[u][1] = s * dx * dy; v[u][2] = s * dy * dy;
                    v[u][3] = rho_ba * gv; v[u][4] = rx * gv;    v[u][5] = ry * gv;
                    cst[e0 + u] = __floats2half2_rn(0.5f * rx * gv, 0.5f * ry * gv);
                }
            }
            seg_reduce4<6>(k, v, acc6);
        }
        __syncthreads();

        // ---- pinv (one lane per node), JAX cutoff semantics ----
        if (tid < NPB) {
            float a = acc6[6*tid], b = acc6[6*tid+1], cc = acc6[6*tid+2];
            float half_tr   = 0.5f * (a + cc);
            float half_diff = 0.5f * (a - cc);
            float disc = sqrtf(half_diff * half_diff + b * b);
            float l1 = half_tr + disc, l2 = half_tr - disc;
            float smax = fmaxf(fabsf(l1), fabsf(l2));
            float cutoff = 2.3841858e-6f * smax;   // rcond = 10*max(2,2)*eps_f32
            float i00 = 0.f, i01 = 0.f, i11 = 0.f;
            if (fabsf(l2) > cutoff) {
                float inv = 1.0f / (a * cc - b * b);
                i00 =  cc * inv; i01 = -b * inv; i11 = a * inv;
            } else if (fabsf(l1) > cutoff) {
                float vax = b,       vay = l1 - a;
                float vbx = l1 - cc, vby = b;
                float na = vax*vax + vay*vay, nb = vbx*vbx + vby*vby;
                float vx, vy, n2;
                if (nb >= na) { vx = vbx; vy = vby; n2 = nb; }
                else          { vx = vax; vy = vay; n2 = na; }
                float inv = 1.0f / (l1 * n2);
                i00 = vx*vx*inv; i01 = vx*vy*inv; i11 = vy*vy*inv;
            }
            Lild[3*tid] = i00; Lild[3*tid+1] = i01; Lild[3*tid+2] = i11;
        }
        __syncthreads();

        // ---- phase C: gradRho from stash ----
#pragma unroll
        for (int c = 0; c < SMAX; ++c) {
            long ebw = beg4 + ((long)c * BLOCKT + waveBase) * 4;
            if (ebw < (long)end) {
                int k[4]; float v[4][2];
#pragma unroll
                for (int u = 0; u < 4; ++u) {
                    int li = li_s[c*4+u];
                    k[u] = li; v[u][0] = v[u][1] = 0.f;
                    if (li >= 0) {
                        float gwx = gwx_s[c*4+u], gwy = gwy_s[c*4+u];
                        float L0 = Lild[3*li], L1 = Lild[3*li+1], L2v = Lild[3*li+2];
                        float gx = L0 * gwx + L1 * gwy;
                        float gy = L1 * gwx + L2v * gwy;
                        float dm = fabsf(gwx) + fabsf(gwy);
                        float nm = fabsf(gx) + fabsf(gy);
                        float change = fabsf(nm - dm) / (dm + 1e-4f * H);
                        if (!(change < 0.1f)) { gx = gwx; gy = gwy; }   // NaN -> fallback
                        v[u][0] = val_s[c*4+u] * gx;
                        v[u][1] = val_s[c*4+u] * gy;
                    }
                }
                seg_reduce4<2>(k, v, gld);
            }
        }
        for (int c = SMAX; ; ++c) {   // overflow recompute (rare)
            long ebw = beg4 + ((long)c * BLOCKT + waveBase) * 4;
            if (ebw >= (long)end) break;
            long e0 = beg4 + ((long)c * BLOCKT + tid) * 4;
            EW wd; load_win(e0, beg, end, E, ej, qarr, dirs, wd);
            int k[4]; float v[4][2];
#pragma unroll
            for (int u = 0; u < 4; ++u) {
                k[u] = -1; v[u][0] = v[u][1] = 0.f;
                if (wd.okv[u]) {
                    int li = li_search(rp, (int)(e0 + u));
                    float q = wd.qv[u], dx = wd.dxv[u], dy = wd.dyv[u];
                    float2 vdj = vd[wd.jv[u]];
                    float w2 = wendland_dkdq(q) * INV_H3;
                    float gwx = dx * w2, gwy = dy * w2;
                    float L0 = Lild[3*li], L1 = Lild[3*li+1], L2v = Lild[3*li+2];
                    float gx = L0 * gwx + L1 * gwy;
                    float gy = L1 * gwx + L2v * gwy;
                    float dm = fabsf(gwx) + fabsf(gwy);
                    float nm = fabsf(gx) + fabsf(gy);
                    float change = fabsf(nm - dm) / (dm + 1e-4f * H);
                    if (!(change < 0.1f)) { gx = gwx; gy = gwy; }
                    float val = 2.f * REST_RHO * (vdj.y - vdl[li].y) * vdj.x;
                    k[u] = li; v[u][0] = val * gx; v[u][1] = val * gy;
                }
            }
            seg_reduce4<2>(k, v, gld);
        }
        __syncthreads();
        if (tid < NPB && n0 + tid < N) {
            float gx = gld[2*tid], gy = gld[2*tid+1];
            g2[n0 + tid]   = make_float2(gx, gy);
            outp[n0 + tid] = acc6[6*tid+3] + 0.5f * (gx * acc6[6*tid+4] + gy * acc6[6*tid+5]);
        }
    }
}

// Pass D (term 3 only): out = K_OUT * (outp + sum_e <g[j], c_e>), persistent.
__global__ __launch_bounds__(BLOCKT, 4)
void k_D(const int* __restrict__ ei, const int* __restrict__ ej,
         const __half2* __restrict__ cst,
         const float2* __restrict__ g2, const float* __restrict__ outp,
         const int* __restrict__ rowptr, float* __restrict__ out,
         int* __restrict__ tickets, int N, int E, int nwin) {
    __shared__ float outl[NPB];
    __shared__ int   wsh;
    const int tid = threadIdx.x;
    const int waveBase = tid & ~(WAVE - 1);

    for (;;) {
        if (tid == 0) wsh = atomicAdd(&tickets[1], 1);
        __syncthreads();
        const int w = wsh;
        if (w >= nwin) break;

        const int n0  = w * NPB;
        const int nHi = min(n0 + NPB, N);
        if (tid < NPB) outl[tid] = 0.f;
        __syncthreads();
        const int  beg = rowptr[n0], end = rowptr[nHi];
        const long beg4 = (long)beg & ~3L;

        for (int c = 0; ; ++c) {
            long ebw = beg4 + ((long)c * BLOCKT + waveBase) * 4;
            if (ebw >= (long)end) break;
            long e0 = beg4 + ((long)c * BLOCKT + tid) * 4;
            int iv[4], jv[4]; float cv[4]; bool okv[4];
            if (e0 + 3 < (long)E) {
                int4   i4 = *(const int4*)(ei + e0);
                int4   j4 = *(const int4*)(ej + e0);
                float4 c4 = ((const float4*)cst)[e0 >> 2];
                iv[0]=i4.x; iv[1]=i4.y; iv[2]=i4.z; iv[3]=i4.w;
                jv[0]=j4.x; jv[1]=j4.y; jv[2]=j4.z; jv[3]=j4.w;
                cv[0]=c4.x; cv[1]=c4.y; cv[2]=c4.z; cv[3]=c4.w;
            } else {
#pragma unroll
                for (int u = 0; u < 4; ++u) {
                    long e = e0 + u;
                    if (e < (long)E) { iv[u] = ei[e]; jv[u] = ej[e]; cv[u] = h2_as_f(cst[e]); }
                    else             { iv[u] = 0;     jv[u] = 0;     cv[u] = 0.f; }
                }
            }
#pragma unroll
            for (int u = 0; u < 4; ++u) {
                long e = e0 + u;
                okv[u] = (e >= (long)beg) && (e < (long)end);
            }
            // all 4 gathers issued before use
            float2 gj4[4];
#pragma unroll
            for (int u = 0; u < 4; ++u)
                gj4[u] = okv[u] ? g2[jv[u]] : make_float2(0.f, 0.f);
            int k[4]; float v[4][1];
#pragma unroll
            for (int u = 0; u < 4; ++u) {
                k[u] = -1; v[u][0] = 0.f;
                if (okv[u]) {
                    __half2 ch = f_as_h2(cv[u]);
                    k[u] = iv[u] - n0;                     // direct key, no search
                    v[u][0] = gj4[u].x * __low2float(ch) + gj4[u].y * __high2float(ch);
                }
            }
            seg_reduce4<1>(k, v, outl);
        }
        __syncthreads();
        if (tid < NPB && n0 + tid < N)
            out[n0 + tid] = K_OUT * (outp[n0 + tid] + outl[tid]);
    }
}

extern "C" void kernel_launch(void* const* d_in, const int* in_sizes, int n_in,
                              void* d_out, int out_size, void* d_ws, size_t ws_size,
                              hipStream_t stream) {
    const float*  vol  = (const float*)d_in[1];
    const float*  dens = (const float*)d_in[2];
    const float2* dirs = (const float2*)d_in[3];
    const float*  qarr = (const float*)d_in[4];
    const int*    ei   = (const int*)d_in[5];
    const int*    ej   = (const int*)d_in[6];
    const int N = in_sizes[1];
    const int E = in_sizes[4];
    const int nwin = (N + NPB - 1) / NPB;

    // ws: rowptr int[N+1] | vd f2[N] | g2 f2[N] | outp f[N] | cst h2[E] | tickets
    size_t off = 0;
    auto alloc = [&](size_t bytes) { void* r = (char*)d_ws + off;
                                     off = (off + bytes + 15) & ~(size_t)15; return r; };
    int*     rowptr  = (int*)    alloc((size_t)(N + 1) * 4);
    float2*  vd      = (float2*) alloc((size_t)N * 8);
    float2*  g2      = (float2*) alloc((size_t)N * 8);
    float*   outp    = (float*)  alloc((size_t)N * 4);
    __half2* cst     = (__half2*)alloc((size_t)E * 4);
    int*     tickets = (int*)    alloc(2 * sizeof(int));
    float*   out     = (float*)d_out;

    const int tb = 256;
    const int gP = (E + 1 + tb - 1) / tb;
    const int gB = (nwin < PBLOCKS) ? nwin : PBLOCKS;

    k_prep<<<gP, tb, 0, stream>>>(ei, vol, dens, rowptr, vd, tickets, N, E);
    k_AC  <<<gB, BLOCKT, 0, stream>>>(ej, qarr, dirs, vd, rowptr, cst, g2, outp,
                                      tickets, N, E, nwin);
    k_D   <<<gB, BLOCKT, 0, stream>>>(ei, ej, cst, g2, outp, rowptr, out,
                                      tickets, N, E, nwin);
}

// Round 6
// 266.793 us; speedup vs baseline: 1.3343x; 1.3343x over previous
//
#include <hip/hip_runtime.h>
#include <hip/hip_fp16.h>
#include <math.h>

#define BLOCKT 256
#define NLOOP  4             // nodes per 32-lane group per block
#define NPBLK  32            // 8 groups * NLOOP nodes per block

// ---- constants from the reference ----
#define KC        2.2281692032865347f   // 7/pi
#define H         0.05f
#define INV_H2    400.0f
#define INV_H3    8000.0f
#define EPS_REF   0.00025f              // h^2 * 0.1
#define K_OUT     0.24261080f           // 2*h*DELTA*C0
#define REST_RHO  1000.0f

__device__ __forceinline__ float wendland_dkdq(float q) {
    float o = 1.f - q;
    return -20.f * q * o * o * o * KC;
}

union H2F { __half2 h; float f; };
__device__ __forceinline__ float   h2_as_f(__half2 h) { H2F u; u.h = h; return u.f; }
__device__ __forceinline__ __half2 f_as_h2(float f)   { H2F u; u.f = f; return u.h; }

// butterfly all-reduce over the 32-lane half-wave; result in every lane
template<int NV>
__device__ __forceinline__ void butterfly32(float v[NV]) {
#pragma unroll
    for (int m = 1; m < 32; m <<= 1) {
#pragma unroll
        for (int c = 0; c < NV; ++c) v[c] += __shfl_xor(v[c], m, 32);
    }
}

// per-edge phase-A terms; also returns gradW, val (phase-C stash) and c_e (half2)
__device__ __forceinline__ void edge_terms(float q, float dx, float dy, float2 vdj,
        float rho_i, float m[6], float& gwx, float& gwy, float& val, __half2& cp) {
    float wq = wendland_dkdq(q);
    float t  = q * wq * INV_H2;          // unit dirs: gradW.r_ba = -t
    float w2 = wq * INV_H3;
    gwx = dx * w2; gwy = dy * w2;
    float rx = -dx * q * H, ry = -dy * q * H;
    float rji2 = rx * rx + ry * ry + EPS_REF;
    float gT = -t / rji2;
    float gv = gT * vdj.x;
    float rho_ba = REST_RHO * vdj.y - rho_i;
    float s = -2.f * vdj.x * t;          // M coefficient (>= 0)
    m[0] = s * dx * dx; m[1] = s * dx * dy; m[2] = s * dy * dy;
    m[3] = rho_ba * gv; m[4] = rx * gv;   m[5] = ry * gv;
    val = 2.f * rho_ba * vdj.x;
    cp = __floats2half2_rn(0.5f * rx * gv, 0.5f * ry * gv);
}

// phase-C per-edge: renormalized gradient + JAX fallback, accumulate val*g
__device__ __forceinline__ void cterm(float gwx, float gwy, float val,
        float i00, float i01, float i11, float g[2]) {
    float gx = i00 * gwx + i01 * gwy;
    float gy = i01 * gwx + i11 * gwy;
    float dm = fabsf(gwx) + fabsf(gwy);
    float nm = fabsf(gx) + fabsf(gy);
    float change = fabsf(nm - dm) / (dm + 1e-4f * H);
    if (!(change < 0.1f)) { gx = gwx; gy = gwy; }   // NaN -> fallback
    g[0] += val * gx; g[1] += val * gy;
}

// rowptr[t] = first edge e with i[e] >= t (i sorted); pack vd=(vol,dens).
__global__ void k_prep(const int* __restrict__ ei, const float* __restrict__ vol,
                       const float* __restrict__ dens, int* __restrict__ rowptr,
                       float2* __restrict__ vd, int N, int E) {
    int e = blockIdx.x * blockDim.x + threadIdx.x;
    if (e <= E) {
        int prev = (e == 0) ? -1 : ei[e - 1];
        int cur  = (e == E) ? N  : ei[e];
        for (int t = prev + 1; t <= cur; ++t) rowptr[t] = e;
    }
    if (e < N) vd[e] = make_float2(vol[e], dens[e]);
}

// ---------------------------------------------------------------------------
// One 32-lane group per node, 2 consecutive edges per lane (deg<=64 in one
// sweep; overflow loop for safety). No LDS, no barriers, no atomics, no
// search: reduction = shfl_xor butterfly; pinv redundant in all lanes.
// ---------------------------------------------------------------------------
__global__ __launch_bounds__(BLOCKT, 4)
void k_AC(const int* __restrict__ ej, const float* __restrict__ qarr,
          const float2* __restrict__ dirs, const float2* __restrict__ vd,
          const int* __restrict__ rowptr, __half2* __restrict__ cst,
          float2* __restrict__ g2, float* __restrict__ outp, int N) {
    const int tid = threadIdx.x;
    const int grp = tid >> 5, sub = tid & 31;
    const int n0 = blockIdx.x * NPBLK;

#pragma unroll 1
    for (int il = 0; il < NLOOP; ++il) {
        const int n = n0 + il * 8 + grp;
        if (n >= N) break;
        const int beg = rowptr[n], end = rowptr[n + 1];
        const float rho_i = REST_RHO * vd[n].y;
        const int base0 = beg & ~1;          // even base -> aligned vector loads

        float acc[6] = {0.f, 0.f, 0.f, 0.f, 0.f, 0.f};
        bool  ok0 = false, ok1 = false;
        float sgx0 = 0.f, sgy0 = 0.f, sv0 = 0.f;   // register stash, slot 0
        float sgx1 = 0.f, sgy1 = 0.f, sv1 = 0.f;   // register stash, slot 1

        {   // ---- sweep 0 (deg <= 64), stashed ----
            const int e0 = base0 + 2 * sub;
            int j0 = 0, j1 = 0;
            float q0 = 0.f, q1 = 0.f, dx0 = 0.f, dy0 = 0.f, dx1 = 0.f, dy1 = 0.f;
            if (e0 + 1 < end) {
                int2   jj = *(const int2*)(ej + e0);
                float2 qq = *(const float2*)(qarr + e0);
                float4 dd = *(const float4*)((const float*)dirs + 2 * e0);
                j0 = jj.x; j1 = jj.y; q0 = qq.x; q1 = qq.y;
                dx0 = dd.x; dy0 = dd.y; dx1 = dd.z; dy1 = dd.w;
                ok0 = (e0 >= beg); ok1 = true;
            } else if (e0 < end) {
                j0 = ej[e0]; q0 = qarr[e0];
                float2 d0 = dirs[e0]; dx0 = d0.x; dy0 = d0.y;
                ok0 = (e0 >= beg);
            }
            float2 vdj0 = ok0 ? vd[j0] : make_float2(0.f, 0.f);
            float2 vdj1 = ok1 ? vd[j1] : make_float2(0.f, 0.f);
            __half2 cp0 = __floats2half2_rn(0.f, 0.f), cp1 = cp0;
            if (ok0) {
                float m[6];
                edge_terms(q0, dx0, dy0, vdj0, rho_i, m, sgx0, sgy0, sv0, cp0);
#pragma unroll
                for (int c = 0; c < 6; ++c) acc[c] += m[c];
            }
            if (ok1) {
                float m[6];
                edge_terms(q1, dx1, dy1, vdj1, rho_i, m, sgx1, sgy1, sv1, cp1);
#pragma unroll
                for (int c = 0; c < 6; ++c) acc[c] += m[c];
            }
            if (ok0 && ok1)
                *(float2*)((float*)cst + e0) = make_float2(h2_as_f(cp0), h2_as_f(cp1));
            else if (ok0) cst[e0] = cp0;
            else if (ok1) cst[e0 + 1] = cp1;
        }
        // ---- overflow sweeps (deg > 64; essentially never) ----
        for (int base = base0 + 64; base < end; base += 64) {
            const int e0 = base + 2 * sub;
            int jj0 = 0, jj1 = 0;
            float tq0 = 0.f, tq1 = 0.f, tdx0 = 0.f, tdy0 = 0.f, tdx1 = 0.f, tdy1 = 0.f;
            bool o0 = false, o1 = false;
            if (e0 + 1 < end) {
                int2   jj = *(const int2*)(ej + e0);
                float2 qq = *(const float2*)(qarr + e0);
                float4 dd = *(const float4*)((const float*)dirs + 2 * e0);
                jj0 = jj.x; jj1 = jj.y; tq0 = qq.x; tq1 = qq.y;
                tdx0 = dd.x; tdy0 = dd.y; tdx1 = dd.z; tdy1 = dd.w;
                o0 = true; o1 = true;
            } else if (e0 < end) {
                jj0 = ej[e0]; tq0 = qarr[e0];
                float2 d0 = dirs[e0]; tdx0 = d0.x; tdy0 = d0.y;
                o0 = true;
            }
            float2 vdj0 = o0 ? vd[jj0] : make_float2(0.f, 0.f);
            float2 vdj1 = o1 ? vd[jj1] : make_float2(0.f, 0.f);
            __half2 cp0 = __floats2half2_rn(0.f, 0.f), cp1 = cp0;
            float du0, du1, du2;
            if (o0) {
                float m[6];
                edge_terms(tq0, tdx0, tdy0, vdj0, rho_i, m, du0, du1, du2, cp0);
#pragma unroll
                for (int c = 0; c < 6; ++c) acc[c] += m[c];
            }
            if (o1) {
                float m[6];
                edge_terms(tq1, tdx1, tdy1, vdj1, rho_i, m, du0, du1, du2, cp1);
#pragma unroll
                for (int c = 0; c < 6; ++c) acc[c] += m[c];
            }
            if (o0 && o1)
                *(float2*)((float*)cst + e0) = make_float2(h2_as_f(cp0), h2_as_f(cp1));
            else if (o0) cst[e0] = cp0;
            else if (o1) cst[e0 + 1] = cp1;
        }

        butterfly32<6>(acc);   // full sums in every lane

        // ---- pinv of [[a,b],[b,c]] in every lane (JAX cutoff semantics) ----
        float i00 = 0.f, i01 = 0.f, i11 = 0.f;
        {
            float a = acc[0], b = acc[1], cc2 = acc[2];
            float half_tr = 0.5f * (a + cc2);
            float half_df = 0.5f * (a - cc2);
            float disc = sqrtf(half_df * half_df + b * b);
            float l1 = half_tr + disc, l2 = half_tr - disc;
            float smax = fmaxf(fabsf(l1), fabsf(l2));
            float cutoff = 2.3841858e-6f * smax;   // rcond = 10*max(2,2)*eps_f32
            if (fabsf(l2) > cutoff) {
                float inv = 1.0f / (a * cc2 - b * b);
                i00 = cc2 * inv; i01 = -b * inv; i11 = a * inv;
            } else if (fabsf(l1) > cutoff) {
                float vax = b,        vay = l1 - a;
                float vbx = l1 - cc2, vby = b;
                float na = vax * vax + vay * vay, nb = vbx * vbx + vby * vby;
                float vx, vy, n2;
                if (nb >= na) { vx = vbx; vy = vby; n2 = nb; }
                else          { vx = vax; vy = vay; n2 = na; }
                float inv = 1.0f / (l1 * n2);
                i00 = vx * vx * inv; i01 = vx * vy * inv; i11 = vy * vy * inv;
            }
        }

        // ---- phase C from register stash ----
        float g[2] = {0.f, 0.f};
        if (ok0) cterm(sgx0, sgy0, sv0, i00, i01, i11, g);
        if (ok1) cterm(sgx1, sgy1, sv1, i00, i01, i11, g);
        for (int base = base0 + 64; base < end; base += 64) {   // overflow reload
            const int e0 = base + 2 * sub;
            int jj0 = 0, jj1 = 0;
            float tq0 = 0.f, tq1 = 0.f, tdx0 = 0.f, tdy0 = 0.f, tdx1 = 0.f, tdy1 = 0.f;
            bool o0 = false, o1 = false;
            if (e0 + 1 < end) {
                int2   jj = *(const int2*)(ej + e0);
                float2 qq = *(const float2*)(qarr + e0);
                float4 dd = *(const float4*)((const float*)dirs + 2 * e0);
                jj0 = jj.x; jj1 = jj.y; tq0 = qq.x; tq1 = qq.y;
                tdx0 = dd.x; tdy0 = dd.y; tdx1 = dd.z; tdy1 = dd.w;
                o0 = true; o1 = true;
            } else if (e0 < end) {
                jj0 = ej[e0]; tq0 = qarr[e0];
                float2 d0 = dirs[e0]; tdx0 = d0.x; tdy0 = d0.y;
                o0 = true;
            }
            if (o0) {
                float2 vdj = vd[jj0];
                float w2 = wendland_dkdq(tq0) * INV_H3;
                cterm(tdx0 * w2, tdy0 * w2,
                      2.f * (REST_RHO * vdj.y - rho_i) * vdj.x, i00, i01, i11, g);
            }
            if (o1) {
                float2 vdj = vd[jj1];
                float w2 = wendland_dkdq(tq1) * INV_H3;
                cterm(tdx1 * w2, tdy1 * w2,
                      2.f * (REST_RHO * vdj.y - rho_i) * vdj.x, i00, i01, i11, g);
            }
        }
        butterfly32<2>(g);
        if (sub == 0) {
            g2[n]   = make_float2(g[0], g[1]);
            outp[n] = acc[3] + 0.5f * (g[0] * acc[4] + g[1] * acc[5]);
        }
    }
}

// Pass D: out = K_OUT * (outp + sum_e <g2[j], c_e>), wave-per-node.
__global__ __launch_bounds__(BLOCKT, 4)
void k_D(const int* __restrict__ ej, const __half2* __restrict__ cst,
         const float2* __restrict__ g2, const float* __restrict__ outp,
         const int* __restrict__ rowptr, float* __restrict__ out, int N) {
    const int tid = threadIdx.x;
    const int grp = tid >> 5, sub = tid & 31;
    const int n0 = blockIdx.x * NPBLK;

#pragma unroll 1
    for (int il = 0; il < NLOOP; ++il) {
        const int n = n0 + il * 8 + grp;
        if (n >= N) break;
        const int beg = rowptr[n], end = rowptr[n + 1];
        const int base0 = beg & ~1;
        float acc[1] = {0.f};
#pragma unroll 1
        for (int base = base0; base < end; base += 64) {
            const int e0 = base + 2 * sub;
            int j0 = 0, j1 = 0; float c0 = 0.f, c1 = 0.f;
            bool ok0 = false, ok1 = false;
            if (e0 + 1 < end) {
                int2   jj = *(const int2*)(ej + e0);
                float2 cc = *(const float2*)((const float*)cst + e0);
                j0 = jj.x; j1 = jj.y; c0 = cc.x; c1 = cc.y;
                ok0 = (e0 >= beg); ok1 = true;
            } else if (e0 < end) {
                j0 = ej[e0]; c0 = h2_as_f(cst[e0]); ok0 = (e0 >= beg);
            }
            float2 gj0 = ok0 ? g2[j0] : make_float2(0.f, 0.f);
            float2 gj1 = ok1 ? g2[j1] : make_float2(0.f, 0.f);
            if (ok0) {
                __half2 ch = f_as_h2(c0);
                acc[0] += gj0.x * __low2float(ch) + gj0.y * __high2float(ch);
            }
            if (ok1) {
                __half2 ch = f_as_h2(c1);
                acc[0] += gj1.x * __low2float(ch) + gj1.y * __high2float(ch);
            }
        }
        butterfly32<1>(acc);
        if (sub == 0) out[n] = K_OUT * (outp[n] + acc[0]);
    }
}

extern "C" void kernel_launch(void* const* d_in, const int* in_sizes, int n_in,
                              void* d_out, int out_size, void* d_ws, size_t ws_size,
                              hipStream_t stream) {
    const float*  vol  = (const float*)d_in[1];
    const float*  dens = (const float*)d_in[2];
    const float2* dirs = (const float2*)d_in[3];
    const float*  qarr = (const float*)d_in[4];
    const int*    ei   = (const int*)d_in[5];
    const int*    ej   = (const int*)d_in[6];
    const int N = in_sizes[1];
    const int E = in_sizes[4];

    // ws: rowptr int[N+1] | vd f2[N] | g2 f2[N] | outp f[N] | cst h2[E]
    size_t off = 0;
    auto alloc = [&](size_t bytes) { void* r = (char*)d_ws + off;
                                     off = (off + bytes + 15) & ~(size_t)15; return r; };
    int*     rowptr = (int*)    alloc((size_t)(N + 1) * 4);
    float2*  vd     = (float2*) alloc((size_t)N * 8);
    float2*  g2     = (float2*) alloc((size_t)N * 8);
    float*   outp   = (float*)  alloc((size_t)N * 4);
    __half2* cst    = (__half2*)alloc((size_t)E * 4);
    float*   out    = (float*)d_out;

    const int tb = 256;
    const int gP = (E + 1 + tb - 1) / tb;
    const int gN = (N + NPBLK - 1) / NPBLK;

    k_prep<<<gP, tb, 0, stream>>>(ei, vol, dens, rowptr, vd, N, E);
    k_AC  <<<gN, BLOCKT, 0, stream>>>(ej, qarr, dirs, vd, rowptr, cst, g2, outp, N);
    k_D   <<<gN, BLOCKT, 0, stream>>>(ej, cst, g2, outp, rowptr, out, N);
}